// Round 1
// 1182.985 us; speedup vs baseline: 1.4961x; 1.4961x over previous
//
#include <hip/hip_runtime.h>
#include <hip/hip_bf16.h>
#include <stdint.h>

// Problem constants
#define NT 4096      // tokens
#define ND 2048      // hidden dim
#define NE 16        // experts
#define NI 1408      // intermediate dim
#define NK 4         // top-k
#define NTK (NT*NK)  // 16384 pair-rows

typedef __attribute__((ext_vector_type(8))) short bf16x8;   // 8 bf16 = 4 VGPRs (MFMA a/b frag)
typedef __attribute__((ext_vector_type(4))) float f32x4;    // MFMA 16x16 acc frag

__device__ __forceinline__ short f2b(float f){
  uint32_t u = __float_as_uint(f);
  uint32_t r = (u + 0x7fffu + ((u >> 16) & 1u)) >> 16;   // RNE
  return (short)(uint16_t)r;
}
__device__ __forceinline__ float b2f(short s){
  return __uint_as_float(((uint32_t)(uint16_t)s) << 16);
}

// async 16B global -> LDS (wave-uniform LDS base + lane*16; per-lane global addr)
__device__ __forceinline__ void gl16(const void* g, void* l){
  __builtin_amdgcn_global_load_lds(
      (const __attribute__((address_space(1))) void*)g,
      (__attribute__((address_space(3))) void*)l, 16, 0, 0);
}

// Workspace int layout (wsi = (int*)d_ws):
// [0..16)      counts per expert
// [16..32)     scatter cursors
// [32]         flag_bf16 (1 = inputs bf16, 0 = fp32)
// [33]         n_work64   [34] n_work128
// [40..57)     offsets (exclusive prefix of counts)
// [64..1152)   work64 list: int4 {e, row_base, rows, 0} x 272
// [2048..2688) work128 list: int4 {e, row_base, rows, 0} x 160
// [3584..3840) zero page (1 KB, 16B aligned) for invalid-row global_load_lds
// [4096..4096+NTK) list: pair id p = t*NK+k, grouped by expert
// byte 262144:             H   bf16 NTK x NI   (46.14 MB)
// byte 262144+H:           xb  bf16 NT x ND    (16.78 MB)   } big-ws path only
// byte ...+xb:             w0b bf16 E x NI x ND (92.27 MB)  }
// byte ...+w0b:            w1b bf16 E x NI x ND (92.27 MB)  }
// w2b bf16 E x ND x NI overlays w0b after pass1.

// ---------------- routing ----------------

__global__ void detect_init_kernel(const unsigned short* xu, int* wsi){
  const int tid = threadIdx.x;
  if (tid < 64) wsi[tid] = 0;     // counts, cursors, flag, n_work
  wsi[3584 + tid] = 0;            // zero page
  __shared__ int red[256];
  // If x is genuine bf16 N(0,1), no element has |v| >= 32 (exp field >= 132).
  // If x is fp32, the low halves of each float are ~uniform bits -> ~48% trip it.
  int c = 0;
  for (int i = tid; i < 8192; i += 256){
    int ex = (xu[i] >> 7) & 0xff;
    c += (ex >= 132) ? 1 : 0;
  }
  red[tid] = c;
  __syncthreads();
  if (tid == 0){
    int s = 0;
    for (int i = 0; i < 256; i++) s += red[i];
    wsi[32] = (s < 64) ? 1 : 0;
  }
}

__global__ void hist_kernel(const int* __restrict__ sel, int* wsi){
  int i = blockIdx.x * 256 + threadIdx.x;
  if (i < NTK) atomicAdd(&wsi[sel[i]], 1);
}

__global__ void plan_kernel(int* wsi){
  if (threadIdx.x != 0) return;
  int4* work64  = (int4*)(wsi + 64);
  int4* work128 = (int4*)(wsi + 2048);
  int off = 0, nw = 0, nw128 = 0;
  for (int e = 0; e < NE; e++){
    int c = wsi[e];
    wsi[40 + e] = off;
    for (int mt = 0; mt * 64 < c; mt++){
      int rem = c - mt * 64;
      work64[nw].x = e; work64[nw].y = off + mt * 64;
      work64[nw].z = rem < 64 ? rem : 64; work64[nw].w = 0;
      nw++;
    }
    for (int mt = 0; mt * 128 < c; mt++){
      int rem = c - mt * 128;
      work128[nw128].x = e; work128[nw128].y = off + mt * 128;
      work128[nw128].z = rem < 128 ? rem : 128; work128[nw128].w = 0;
      nw128++;
    }
    off += c;
  }
  wsi[33] = nw;
  wsi[34] = nw128;
}

__global__ void scatter_kernel(const int* __restrict__ sel, int* wsi, int* list){
  int i = blockIdx.x * 256 + threadIdx.x;
  if (i < NTK){
    int e = sel[i];
    int pos = atomicAdd(&wsi[16 + e], 1);
    list[wsi[40 + e] + pos] = i;
  }
}

// ---------------- fp32 -> bf16 conversion (big-ws path, only when flag==0) ----------------

__global__ __launch_bounds__(256)
void conv_kernel(const float* __restrict__ src, short* __restrict__ dst,
                 int n8, const int* __restrict__ wsi){
  if (wsi[32]) return;   // inputs already bf16
  int stride = gridDim.x * 256;
  for (int i = blockIdx.x * 256 + threadIdx.x; i < n8; i += stride){
    const float4* s = (const float4*)(src + (size_t)i * 8);
    float4 a = s[0], b = s[1];
    bf16x8 v;
    v[0]=f2b(a.x); v[1]=f2b(a.y); v[2]=f2b(a.z); v[3]=f2b(a.w);
    v[4]=f2b(b.x); v[5]=f2b(b.y); v[6]=f2b(b.z); v[7]=f2b(b.w);
    *(bf16x8*)(dst + (size_t)i * 8) = v;
  }
}

// ---------------- big-ws pass 1: BM=128, BN=64 (w0 & w1 each), BK=32, global_load_lds ----------------

template<int ISB>
__global__ __launch_bounds__(256)
void pass1b_kernel(const void* __restrict__ xg, const void* __restrict__ w0g,
                   const void* __restrict__ w1g,
                   const short* __restrict__ xb, const short* __restrict__ w0b,
                   const short* __restrict__ w1b,
                   const int* __restrict__ wsi, const int* __restrict__ list,
                   short* __restrict__ H)
{
  if (wsi[32] != ISB) return;
  if ((int)blockIdx.x >= wsi[34]) return;
  const int4 wk = ((const int4*)(wsi + 2048))[blockIdx.x];
  const int e = wk.x, row_base = wk.y, rows = wk.z;
  const int n0 = blockIdx.y * 64;

  __shared__ short As [128 * 32];   // 8 KB
  __shared__ short B0s[ 64 * 32];   // 4 KB
  __shared__ short B1s[ 64 * 32];   // 4 KB

  const int tid = threadIdx.x;
  const short* xs  = ISB ? (const short*)xg  : xb;
  const short* w0s = ISB ? (const short*)w0g : w0b;
  const short* w1s = ISB ? (const short*)w1g : w1b;
  const short* zp  = (const short*)(wsi + 3584);

  // staging: A = 512 slots (2/thread), B0/B1 = 256 slots (1/thread); slot = 16B
  const int rr = tid >> 2;              // 0..63
  const int cc = (tid & 3) << 3;        // k-offset 0/8/16/24
  const bool va0 = rr < rows;
  const bool va1 = (64 + rr) < rows;
  const int t0 = va0 ? (list[row_base + rr] >> 2) : 0;
  const int t1 = va1 ? (list[row_base + 64 + rr] >> 2) : 0;
  const short* ag0 = va0 ? xs + (size_t)t0 * ND + cc : zp;
  const short* ag1 = va1 ? xs + (size_t)t1 * ND + cc : zp;
  const int sa0 = va0 ? 32 : 0;
  const int sa1 = va1 ? 32 : 0;
  const short* bg0 = w0s + ((size_t)e * NI + n0 + rr) * ND + cc;
  const short* bg1 = w1s + ((size_t)e * NI + n0 + rr) * ND + cc;

  short* la0 = &As [(size_t)tid * 8];
  short* la1 = &As [((size_t)tid + 256) * 8];
  short* lb0 = &B0s[(size_t)tid * 8];
  short* lb1 = &B1s[(size_t)tid * 8];

  const int lane = tid & 63;
  const int wv = tid >> 6;
  const int wm = (wv >> 1) << 6;   // 0/64
  const int wn = (wv & 1) << 5;    // 0/32
  const int r16 = lane & 15;
  const int qd  = lane >> 4;
  const int qd8 = qd << 3;

  f32x4 acc0[4][2] = {};
  f32x4 acc1[4][2] = {};

  for (int kt = 0; kt < ND; kt += 32){
    __syncthreads();
    gl16(ag0, la0); gl16(ag1, la1);
    gl16(bg0, lb0); gl16(bg1, lb1);
    ag0 += sa0; ag1 += sa1; bg0 += 32; bg1 += 32;
    __syncthreads();   // drains vmcnt before LDS reads
    bf16x8 af[4], b0f[2], b1f[2];
    #pragma unroll
    for (int mi = 0; mi < 4; mi++)
      af[mi] = *(const bf16x8*)&As[(wm + mi*16 + r16) * 32 + qd8];
    #pragma unroll
    for (int ni = 0; ni < 2; ni++){
      b0f[ni] = *(const bf16x8*)&B0s[(wn + ni*16 + r16) * 32 + qd8];
      b1f[ni] = *(const bf16x8*)&B1s[(wn + ni*16 + r16) * 32 + qd8];
    }
    #pragma unroll
    for (int mi = 0; mi < 4; mi++)
      #pragma unroll
      for (int ni = 0; ni < 2; ni++){
        acc0[mi][ni] = __builtin_amdgcn_mfma_f32_16x16x32_bf16(af[mi], b0f[ni], acc0[mi][ni], 0, 0, 0);
        acc1[mi][ni] = __builtin_amdgcn_mfma_f32_16x16x32_bf16(af[mi], b1f[ni], acc1[mi][ni], 0, 0, 0);
      }
  }

  // epilogue: C[m = qd*4+reg][n = lane&15]
  #pragma unroll
  for (int mi = 0; mi < 4; mi++){
    #pragma unroll
    for (int r = 0; r < 4; r++){
      int m = wm + mi*16 + qd*4 + r;
      if (m >= rows) continue;
      size_t hrow = (size_t)(row_base + m) * NI + n0 + wn;
      #pragma unroll
      for (int ni = 0; ni < 2; ni++){
        float a0v = acc0[mi][ni][r];
        float a1v = acc1[mi][ni][r];
        float hv = (a0v / (1.f + __expf(-a0v))) * a1v;   // silu(a0)*a1
        H[hrow + ni*16 + r16] = f2b(hv);
      }
    }
  }
}

// ---------------- big-ws pass 2: BM=128, BN=128, BK=32, global_load_lds ----------------

template<int ISB>
__global__ __launch_bounds__(256)
void pass2b_kernel(const void* __restrict__ w2g, const void* __restrict__ rw,
                   const short* __restrict__ w2b,
                   const int* __restrict__ wsi, const int* __restrict__ list,
                   const short* __restrict__ H, void* __restrict__ out)
{
  if (wsi[32] != ISB) return;
  if ((int)blockIdx.x >= wsi[34]) return;
  const int4 wk = ((const int4*)(wsi + 2048))[blockIdx.x];
  const int e = wk.x, row_base = wk.y, rows = wk.z;
  const int n0 = blockIdx.y * 128;

  __shared__ short As[128 * 32];   // 8 KB
  __shared__ short Bs[128 * 32];   // 8 KB

  const int tid = threadIdx.x;
  const short* ws2 = ISB ? (const short*)w2g : w2b;
  const short* zp  = (const short*)(wsi + 3584);

  const int rr = tid >> 2;
  const int cc = (tid & 3) << 3;
  const bool va0 = rr < rows;
  const bool va1 = (64 + rr) < rows;
  const short* ag0 = va0 ? H + (size_t)(row_base + rr) * NI + cc : zp;
  const short* ag1 = va1 ? H + (size_t)(row_base + 64 + rr) * NI + cc : zp;
  const int sa0 = va0 ? 32 : 0;
  const int sa1 = va1 ? 32 : 0;
  const short* bg0 = ws2 + ((size_t)e * ND + n0 + rr) * NI + cc;
  const short* bg1 = ws2 + ((size_t)e * ND + n0 + 64 + rr) * NI + cc;

  short* la0 = &As[(size_t)tid * 8];
  short* la1 = &As[((size_t)tid + 256) * 8];
  short* lb0 = &Bs[(size_t)tid * 8];
  short* lb1 = &Bs[((size_t)tid + 256) * 8];

  const int lane = tid & 63;
  const int wv = tid >> 6;
  const int wm = (wv >> 1) << 6;   // 0/64
  const int wn = (wv & 1) << 6;    // 0/64
  const int r16 = lane & 15;
  const int qd  = lane >> 4;
  const int qd8 = qd << 3;

  f32x4 acc[4][4] = {};

  for (int kt = 0; kt < NI; kt += 32){
    __syncthreads();
    gl16(ag0, la0); gl16(ag1, la1);
    gl16(bg0, lb0); gl16(bg1, lb1);
    ag0 += sa0; ag1 += sa1; bg0 += 32; bg1 += 32;
    __syncthreads();
    bf16x8 af[4], bf[4];
    #pragma unroll
    for (int mi = 0; mi < 4; mi++)
      af[mi] = *(const bf16x8*)&As[(wm + mi*16 + r16) * 32 + qd8];
    #pragma unroll
    for (int ni = 0; ni < 4; ni++)
      bf[ni] = *(const bf16x8*)&Bs[(wn + ni*16 + r16) * 32 + qd8];
    #pragma unroll
    for (int mi = 0; mi < 4; mi++)
      #pragma unroll
      for (int ni = 0; ni < 4; ni++)
        acc[mi][ni] = __builtin_amdgcn_mfma_f32_16x16x32_bf16(af[mi], bf[ni], acc[mi][ni], 0, 0, 0);
  }

  #pragma unroll
  for (int mi = 0; mi < 4; mi++){
    #pragma unroll
    for (int r = 0; r < 4; r++){
      int m = wm + mi*16 + qd*4 + r;
      if (m >= rows) continue;
      int p = list[row_base + m];
      float sc = ISB ? b2f(((const short*)rw)[p]) : ((const float*)rw)[p];
      size_t orow = (size_t)p * ND + n0 + wn;
      #pragma unroll
      for (int ni = 0; ni < 4; ni++){
        float v = acc[mi][ni][r] * sc;
        if (ISB) ((short*)out)[orow + ni*16 + r16] = f2b(v);
        else     ((float*)out)[orow + ni*16 + r16] = v;
      }
    }
  }
}

// ---------------- fallback (small workspace): previous verified 64x64 path ----------------

template<int ISB>
__device__ __forceinline__ void stage8(short* dst, const void* base, size_t off, bool valid){
  if (ISB){
    bf16x8 v = valid ? *(const bf16x8*)((const short*)base + off) : (bf16x8)0;
    *(bf16x8*)dst = v;
  } else {
    if (valid){
      const float4* s = (const float4*)((const float*)base + off);
      float4 a = s[0], b = s[1];
      dst[0]=f2b(a.x); dst[1]=f2b(a.y); dst[2]=f2b(a.z); dst[3]=f2b(a.w);
      dst[4]=f2b(b.x); dst[5]=f2b(b.y); dst[6]=f2b(b.z); dst[7]=f2b(b.w);
    } else {
      *(bf16x8*)dst = (bf16x8)0;
    }
  }
}

#define LDS_STRIDE 40

template<int ISB>
__global__ __launch_bounds__(256)
void pass1_kernel(const void* __restrict__ x, const void* __restrict__ w0,
                  const void* __restrict__ w1, const int* __restrict__ wsi,
                  const int* __restrict__ list, short* __restrict__ H)
{
  if (wsi[32] != ISB) return;
  if ((int)blockIdx.x >= wsi[33]) return;
  const int4 wk = ((const int4*)(wsi + 64))[blockIdx.x];
  const int e = wk.x, row_base = wk.y, rows = wk.z;
  const int n0 = blockIdx.y * 64;

  __shared__ short As [64 * LDS_STRIDE];
  __shared__ short B0s[64 * LDS_STRIDE];
  __shared__ short B1s[64 * LDS_STRIDE];

  const int tid = threadIdx.x;
  const int lr  = tid >> 2;
  const int c8  = (tid & 3) << 3;
  const bool avalid = lr < rows;
  size_t abase = 0;
  if (avalid){
    int tok = list[row_base + lr] >> 2;
    abase = (size_t)tok * ND + c8;
  }
  const size_t bbase = ((size_t)e * NI + (size_t)(n0 + lr)) * (size_t)ND + c8;

  const int lane = tid & 63;
  const int wv = tid >> 6;
  const int wm = (wv >> 1) << 5;
  const int wn = (wv & 1) << 5;
  const int r16 = lane & 15;
  const int qd  = lane >> 4;
  const int qd8 = qd << 3;

  f32x4 acc0[2][2] = {};
  f32x4 acc1[2][2] = {};

  short* a_dst  = &As [lr * LDS_STRIDE + c8];
  short* b0_dst = &B0s[lr * LDS_STRIDE + c8];
  short* b1_dst = &B1s[lr * LDS_STRIDE + c8];

  for (int kt = 0; kt < ND; kt += 32){
    __syncthreads();
    stage8<ISB>(a_dst,  x,  abase + kt, avalid);
    stage8<ISB>(b0_dst, w0, bbase + kt, true);
    stage8<ISB>(b1_dst, w1, bbase + kt, true);
    __syncthreads();
    bf16x8 af[2], b0f[2], b1f[2];
    #pragma unroll
    for (int mi = 0; mi < 2; mi++)
      af[mi] = *(const bf16x8*)&As[(wm + mi*16 + r16) * LDS_STRIDE + qd8];
    #pragma unroll
    for (int ni = 0; ni < 2; ni++){
      b0f[ni] = *(const bf16x8*)&B0s[(wn + ni*16 + r16) * LDS_STRIDE + qd8];
      b1f[ni] = *(const bf16x8*)&B1s[(wn + ni*16 + r16) * LDS_STRIDE + qd8];
    }
    #pragma unroll
    for (int mi = 0; mi < 2; mi++)
      #pragma unroll
      for (int ni = 0; ni < 2; ni++){
        acc0[mi][ni] = __builtin_amdgcn_mfma_f32_16x16x32_bf16(af[mi], b0f[ni], acc0[mi][ni], 0, 0, 0);
        acc1[mi][ni] = __builtin_amdgcn_mfma_f32_16x16x32_bf16(af[mi], b1f[ni], acc1[mi][ni], 0, 0, 0);
      }
  }

  #pragma unroll
  for (int mi = 0; mi < 2; mi++){
    #pragma unroll
    for (int r = 0; r < 4; r++){
      int m = wm + mi*16 + qd*4 + r;
      if (m >= rows) continue;
      size_t hrow = (size_t)(row_base + m) * NI + n0;
      #pragma unroll
      for (int ni = 0; ni < 2; ni++){
        float a0v = acc0[mi][ni][r];
        float a1v = acc1[mi][ni][r];
        float hv = (a0v / (1.f + __expf(-a0v))) * a1v;
        H[hrow + wn + ni*16 + r16] = f2b(hv);
      }
    }
  }
}

template<int ISB>
__global__ __launch_bounds__(256)
void pass2_kernel(const void* __restrict__ w2, const void* __restrict__ rw,
                  const int* __restrict__ wsi, const int* __restrict__ list,
                  const short* __restrict__ H, void* __restrict__ out)
{
  if (wsi[32] != ISB) return;
  if ((int)blockIdx.x >= wsi[33]) return;
  const int4 wk = ((const int4*)(wsi + 64))[blockIdx.x];
  const int e = wk.x, row_base = wk.y, rows = wk.z;
  const int n0 = blockIdx.y * 64;

  __shared__ short As[64 * LDS_STRIDE];
  __shared__ short Bs[64 * LDS_STRIDE];

  const int tid = threadIdx.x;
  const int lr  = tid >> 2;
  const int c8  = (tid & 3) << 3;
  const bool avalid = lr < rows;
  const size_t abase = (size_t)(row_base + lr) * NI + c8;
  const size_t bbase = ((size_t)e * ND + (size_t)(n0 + lr)) * (size_t)NI + c8;

  const int lane = tid & 63;
  const int wv = tid >> 6;
  const int wm = (wv >> 1) << 5;
  const int wn = (wv & 1) << 5;
  const int r16 = lane & 15;
  const int qd  = lane >> 4;
  const int qd8 = qd << 3;

  f32x4 acc[2][2] = {};

  short* a_dst = &As[lr * LDS_STRIDE + c8];
  short* b_dst = &Bs[lr * LDS_STRIDE + c8];

  for (int kt = 0; kt < NI; kt += 32){
    __syncthreads();
    {
      bf16x8 v = avalid ? *(const bf16x8*)&H[abase + kt] : (bf16x8)0;
      *(bf16x8*)a_dst = v;
    }
    stage8<ISB>(b_dst, w2, bbase + kt, true);
    __syncthreads();
    bf16x8 af[2], bf[2];
    #pragma unroll
    for (int mi = 0; mi < 2; mi++)
      af[mi] = *(const bf16x8*)&As[(wm + mi*16 + r16) * LDS_STRIDE + qd8];
    #pragma unroll
    for (int ni = 0; ni < 2; ni++)
      bf[ni] = *(const bf16x8*)&Bs[(wn + ni*16 + r16) * LDS_STRIDE + qd8];
    #pragma unroll
    for (int mi = 0; mi < 2; mi++)
      #pragma unroll
      for (int ni = 0; ni < 2; ni++)
        acc[mi][ni] = __builtin_amdgcn_mfma_f32_16x16x32_bf16(af[mi], bf[ni], acc[mi][ni], 0, 0, 0);
  }

  #pragma unroll
  for (int mi = 0; mi < 2; mi++){
    #pragma unroll
    for (int r = 0; r < 4; r++){
      int m = wm + mi*16 + qd*4 + r;
      if (m >= rows) continue;
      int p = list[row_base + m];
      float sc = ISB ? b2f(((const short*)rw)[p]) : ((const float*)rw)[p];
      size_t orow = (size_t)p * ND + n0;
      #pragma unroll
      for (int ni = 0; ni < 2; ni++){
        float v = acc[mi][ni][r] * sc;
        if (ISB) ((short*)out)[orow + wn + ni*16 + r16] = f2b(v);
        else     ((float*)out)[orow + wn + ni*16 + r16] = v;
      }
    }
  }
}

// ---------------- launch ----------------

extern "C" void kernel_launch(void* const* d_in, const int* in_sizes, int n_in,
                              void* d_out, int out_size, void* d_ws, size_t ws_size,
                              hipStream_t stream) {
  (void)in_sizes; (void)n_in; (void)out_size;
  const void* x  = d_in[0];
  const void* w0 = d_in[1];
  const void* w1 = d_in[2];
  const void* w2 = d_in[3];
  const int* sel = (const int*)d_in[4];
  const void* rw = d_in[5];

  int* wsi   = (int*)d_ws;
  int* list  = wsi + 4096;
  short* H   = (short*)((char*)d_ws + 262144);

  const size_t H_BYTES  = (size_t)NTK * NI * 2;          // 46,137,344
  const size_t XB_BYTES = (size_t)NT * ND * 2;           // 16,777,216
  const size_t WB_BYTES = (size_t)NE * NI * ND * 2;      // 92,274,688
  const size_t offX = 262144 + H_BYTES;
  const size_t offW = offX + XB_BYTES;
  const size_t need = offW + 2 * WB_BYTES;               // ~247.7 MB

  detect_init_kernel<<<1, 256, 0, stream>>>((const unsigned short*)x, wsi);
  hist_kernel<<<NTK/256, 256, 0, stream>>>(sel, wsi);
  plan_kernel<<<1, 64, 0, stream>>>(wsi);
  scatter_kernel<<<NTK/256, 256, 0, stream>>>(sel, wsi, list);

  if (ws_size >= need){
    short* xb  = (short*)((char*)d_ws + offX);
    short* w0b = (short*)((char*)d_ws + offW);
    short* w1b = w0b + (size_t)NE * NI * ND;
    short* w2b = w0b;   // overlays w0b AFTER pass1 consumed it (stream-ordered)

    conv_kernel<<<2048, 256, 0, stream>>>((const float*)x,  xb,  NT*ND/8,    wsi);
    conv_kernel<<<2048, 256, 0, stream>>>((const float*)w0, w0b, NE*NI*ND/8, wsi);
    conv_kernel<<<2048, 256, 0, stream>>>((const float*)w1, w1b, NE*NI*ND/8, wsi);

    dim3 g1(160, NI/64);    // 160 x 22
    pass1b_kernel<1><<<g1, 256, 0, stream>>>(x, w0, w1, xb, w0b, w1b, wsi, list, H);
    pass1b_kernel<0><<<g1, 256, 0, stream>>>(x, w0, w1, xb, w0b, w1b, wsi, list, H);

    conv_kernel<<<2048, 256, 0, stream>>>((const float*)w2, w2b, NE*ND*NI/8, wsi);

    dim3 g2(160, ND/128);   // 160 x 16
    pass2b_kernel<1><<<g2, 256, 0, stream>>>(w2, rw, w2b, wsi, list, H, d_out);
    pass2b_kernel<0><<<g2, 256, 0, stream>>>(w2, rw, w2b, wsi, list, H, d_out);
  } else {
    dim3 g1(272, NI/64);
    dim3 g2(272, ND/64);
    pass1_kernel<1><<<g1, 256, 0, stream>>>(x, w0, w1, wsi, list, H);
    pass1_kernel<0><<<g1, 256, 0, stream>>>(x, w0, w1, wsi, list, H);
    pass2_kernel<1><<<g2, 256, 0, stream>>>(w2, rw, wsi, list, H, d_out);
    pass2_kernel<0><<<g2, 256, 0, stream>>>(w2, rw, wsi, list, H, d_out);
  }
}

// Round 2
// 1130.246 us; speedup vs baseline: 1.5659x; 1.0467x over previous
//
#include <hip/hip_runtime.h>
#include <hip/hip_bf16.h>
#include <stdint.h>

// Problem constants
#define NT 4096      // tokens
#define ND 2048      // hidden dim
#define NE 16        // experts
#define NI 1408      // intermediate dim
#define NK 4         // top-k
#define NTK (NT*NK)  // 16384 pair-rows

typedef __attribute__((ext_vector_type(8))) short bf16x8;   // 8 bf16 = 4 VGPRs (MFMA a/b frag)
typedef __attribute__((ext_vector_type(4))) float f32x4;    // MFMA 16x16 acc frag

__device__ __forceinline__ short f2b(float f){
  uint32_t u = __float_as_uint(f);
  uint32_t r = (u + 0x7fffu + ((u >> 16) & 1u)) >> 16;   // RNE
  return (short)(uint16_t)r;
}
__device__ __forceinline__ float b2f(short s){
  return __uint_as_float(((uint32_t)(uint16_t)s) << 16);
}

// async 16B global -> LDS (wave-uniform LDS base + lane*16; per-lane global addr)
__device__ __forceinline__ void gl16(const void* g, void* l){
  __builtin_amdgcn_global_load_lds(
      (const __attribute__((address_space(1))) void*)g,
      (__attribute__((address_space(3))) void*)l, 16, 0, 0);
}

// XCD-chunked bijective swizzle: hardware round-robins linear block id over 8 XCDs;
// remap so each XCD owns a CONTIGUOUS swz range (nwg must be divisible by 8).
// Decompose swz m-fastest: consecutive swz on one XCD = consecutive M-tiles sharing
// the same expert B-tile -> B fetched into exactly one L2.
__device__ __forceinline__ int xcd_swz(int lin, int nwg){
  int cpx = nwg >> 3;
  return (lin & 7) * cpx + (lin >> 3);
}

// Workspace int layout (wsi = (int*)d_ws):
// [0..16)      counts per expert
// [16..32)     scatter cursors
// [32]         flag_bf16 (1 = inputs bf16, 0 = fp32)
// [33]         n_work64   [34] n_work128
// [40..57)     offsets (exclusive prefix of counts)
// [64..1152)   work64 list: int4 {e, row_base, rows, 0} x 272
// [2048..2688) work128 list: int4 {e, row_base, rows, 0} x 160
// [3584..3840) zero page (1 KB, 16B aligned) for invalid-row global_load_lds
// [4096..4096+NTK) list: pair id p = t*NK+k, grouped by expert
// byte 262144:             H   bf16 NTK x NI   (46.14 MB)
// byte 262144+H:           xb  bf16 NT x ND    (16.78 MB)   } big-ws path only
// byte ...+xb:             w0b bf16 E x NI x ND (92.27 MB)  }
// byte ...+w0b:            w1b bf16 E x NI x ND (92.27 MB)  }
// w2b bf16 E x ND x NI overlays w0b after pass1.

// ---------------- routing ----------------

__global__ void detect_init_kernel(const unsigned short* xu, int* wsi){
  const int tid = threadIdx.x;
  if (tid < 64) wsi[tid] = 0;     // counts, cursors, flag, n_work
  wsi[3584 + tid] = 0;            // zero page
  __shared__ int red[256];
  // If x is genuine bf16 N(0,1), no element has |v| >= 32 (exp field >= 132).
  // If x is fp32, the low halves of each float are ~uniform bits -> ~48% trip it.
  int c = 0;
  for (int i = tid; i < 8192; i += 256){
    int ex = (xu[i] >> 7) & 0xff;
    c += (ex >= 132) ? 1 : 0;
  }
  red[tid] = c;
  __syncthreads();
  if (tid == 0){
    int s = 0;
    for (int i = 0; i < 256; i++) s += red[i];
    wsi[32] = (s < 64) ? 1 : 0;
  }
}

__global__ void hist_kernel(const int* __restrict__ sel, int* wsi){
  int i = blockIdx.x * 256 + threadIdx.x;
  if (i < NTK) atomicAdd(&wsi[sel[i]], 1);
}

__global__ void plan_kernel(int* wsi){
  if (threadIdx.x != 0) return;
  int4* work64  = (int4*)(wsi + 64);
  int4* work128 = (int4*)(wsi + 2048);
  int off = 0, nw = 0, nw128 = 0;
  for (int e = 0; e < NE; e++){
    int c = wsi[e];
    wsi[40 + e] = off;
    for (int mt = 0; mt * 64 < c; mt++){
      int rem = c - mt * 64;
      work64[nw].x = e; work64[nw].y = off + mt * 64;
      work64[nw].z = rem < 64 ? rem : 64; work64[nw].w = 0;
      nw++;
    }
    for (int mt = 0; mt * 128 < c; mt++){
      int rem = c - mt * 128;
      work128[nw128].x = e; work128[nw128].y = off + mt * 128;
      work128[nw128].z = rem < 128 ? rem : 128; work128[nw128].w = 0;
      nw128++;
    }
    off += c;
  }
  wsi[33] = nw;
  wsi[34] = nw128;
}

__global__ void scatter_kernel(const int* __restrict__ sel, int* wsi, int* list){
  int i = blockIdx.x * 256 + threadIdx.x;
  if (i < NTK){
    int e = sel[i];
    int pos = atomicAdd(&wsi[16 + e], 1);
    list[wsi[40 + e] + pos] = i;
  }
}

// ---------------- fp32 -> bf16 conversion (big-ws path, only when flag==0) ----------------

__global__ __launch_bounds__(256)
void conv_kernel(const float* __restrict__ src, short* __restrict__ dst,
                 int n8, const int* __restrict__ wsi){
  if (wsi[32]) return;   // inputs already bf16
  int stride = gridDim.x * 256;
  for (int i = blockIdx.x * 256 + threadIdx.x; i < n8; i += stride){
    const float4* s = (const float4*)(src + (size_t)i * 8);
    float4 a = s[0], b = s[1];
    bf16x8 v;
    v[0]=f2b(a.x); v[1]=f2b(a.y); v[2]=f2b(a.z); v[3]=f2b(a.w);
    v[4]=f2b(b.x); v[5]=f2b(b.y); v[6]=f2b(b.z); v[7]=f2b(b.w);
    *(bf16x8*)(dst + (size_t)i * 8) = v;
  }
}

// ---------------- big-ws pass 1: BM=128, BN=128 (w0 & w1 each), BK=32 ----------------
// grid: (160, NI/128=11); 1760 blocks, divisible by 8 for xcd_swz.
// Per K-step per thread: 6 gl16 (A x2, B0 x2, B1 x2); per wave: 32 MFMA.

template<int ISB>
__global__ __launch_bounds__(256, 2)
void pass1b_kernel(const void* __restrict__ xg, const void* __restrict__ w0g,
                   const void* __restrict__ w1g,
                   const short* __restrict__ xb, const short* __restrict__ w0b,
                   const short* __restrict__ w1b,
                   const int* __restrict__ wsi, const int* __restrict__ list,
                   short* __restrict__ H)
{
  if (wsi[32] != ISB) return;
  const int nmt = wsi[34];
  const int lin = blockIdx.x + 160 * blockIdx.y;
  const int swz = xcd_swz(lin, 160 * gridDim.y);
  const int mtile = swz % 160;
  const int ntile = swz / 160;
  if (mtile >= nmt) return;
  const int4 wk = ((const int4*)(wsi + 2048))[mtile];
  const int e = wk.x, row_base = wk.y, rows = wk.z;
  const int n0 = ntile * 128;

  __shared__ short As [128 * 32];   // 8 KB
  __shared__ short B0s[128 * 32];   // 8 KB
  __shared__ short B1s[128 * 32];   // 8 KB

  const int tid = threadIdx.x;
  const short* xs  = ISB ? (const short*)xg  : xb;
  const short* w0s = ISB ? (const short*)w0g : w0b;
  const short* w1s = ISB ? (const short*)w1g : w1b;
  const short* zp  = (const short*)(wsi + 3584);

  // staging: each buffer 512 slots of 16B; thread stages slots {tid, tid+256}
  const int rr = tid >> 2;              // 0..63
  const int cc = (tid & 3) << 3;        // k-offset 0/8/16/24
  const bool va0 = rr < rows;
  const bool va1 = (64 + rr) < rows;
  const int t0 = va0 ? (list[row_base + rr] >> 2) : 0;
  const int t1 = va1 ? (list[row_base + 64 + rr] >> 2) : 0;
  const short* ag0 = va0 ? xs + (size_t)t0 * ND + cc : zp;
  const short* ag1 = va1 ? xs + (size_t)t1 * ND + cc : zp;
  const int sa0 = va0 ? 32 : 0;
  const int sa1 = va1 ? 32 : 0;
  const short* b0g0 = w0s + ((size_t)e * NI + n0 + rr)      * ND + cc;
  const short* b0g1 = w0s + ((size_t)e * NI + n0 + 64 + rr) * ND + cc;
  const short* b1g0 = w1s + ((size_t)e * NI + n0 + rr)      * ND + cc;
  const short* b1g1 = w1s + ((size_t)e * NI + n0 + 64 + rr) * ND + cc;

  short* la0  = &As [(size_t)tid * 8];
  short* la1  = &As [((size_t)tid + 256) * 8];
  short* lb00 = &B0s[(size_t)tid * 8];
  short* lb01 = &B0s[((size_t)tid + 256) * 8];
  short* lb10 = &B1s[(size_t)tid * 8];
  short* lb11 = &B1s[((size_t)tid + 256) * 8];

  const int lane = tid & 63;
  const int wv = tid >> 6;
  const int wm = (wv >> 1) << 6;   // 0/64
  const int wn = (wv & 1) << 6;    // 0/64
  const int r16 = lane & 15;
  const int qd  = lane >> 4;
  const int qd8 = qd << 3;

  f32x4 acc0[4][4] = {};
  f32x4 acc1[4][4] = {};

  for (int kt = 0; kt < ND; kt += 32){
    __syncthreads();
    gl16(ag0,  la0);  gl16(ag1,  la1);
    gl16(b0g0, lb00); gl16(b0g1, lb01);
    gl16(b1g0, lb10); gl16(b1g1, lb11);
    ag0 += sa0; ag1 += sa1;
    b0g0 += 32; b0g1 += 32; b1g0 += 32; b1g1 += 32;
    __syncthreads();   // drains vmcnt before LDS reads
    bf16x8 af[4], b0f[4], b1f[4];
    #pragma unroll
    for (int mi = 0; mi < 4; mi++)
      af[mi] = *(const bf16x8*)&As[(wm + mi*16 + r16) * 32 + qd8];
    #pragma unroll
    for (int ni = 0; ni < 4; ni++){
      b0f[ni] = *(const bf16x8*)&B0s[(wn + ni*16 + r16) * 32 + qd8];
      b1f[ni] = *(const bf16x8*)&B1s[(wn + ni*16 + r16) * 32 + qd8];
    }
    #pragma unroll
    for (int mi = 0; mi < 4; mi++)
      #pragma unroll
      for (int ni = 0; ni < 4; ni++){
        acc0[mi][ni] = __builtin_amdgcn_mfma_f32_16x16x32_bf16(af[mi], b0f[ni], acc0[mi][ni], 0, 0, 0);
        acc1[mi][ni] = __builtin_amdgcn_mfma_f32_16x16x32_bf16(af[mi], b1f[ni], acc1[mi][ni], 0, 0, 0);
      }
  }

  // epilogue: C[m = qd*4+reg][n = lane&15]
  #pragma unroll
  for (int mi = 0; mi < 4; mi++){
    #pragma unroll
    for (int r = 0; r < 4; r++){
      int m = wm + mi*16 + qd*4 + r;
      if (m >= rows) continue;
      size_t hrow = (size_t)(row_base + m) * NI + n0 + wn;
      #pragma unroll
      for (int ni = 0; ni < 4; ni++){
        float a0v = acc0[mi][ni][r];
        float a1v = acc1[mi][ni][r];
        float hv = (a0v / (1.f + __expf(-a0v))) * a1v;   // silu(a0)*a1
        H[hrow + ni*16 + r16] = f2b(hv);
      }
    }
  }
}

// ---------------- big-ws pass 2: BM=128, BN=256, BK=32 ----------------
// grid: (160, ND/256=8); 1280 blocks, divisible by 8.

template<int ISB>
__global__ __launch_bounds__(256, 2)
void pass2b_kernel(const void* __restrict__ w2g, const void* __restrict__ rw,
                   const short* __restrict__ w2b,
                   const int* __restrict__ wsi, const int* __restrict__ list,
                   const short* __restrict__ H, void* __restrict__ out)
{
  if (wsi[32] != ISB) return;
  const int nmt = wsi[34];
  const int lin = blockIdx.x + 160 * blockIdx.y;
  const int swz = xcd_swz(lin, 160 * gridDim.y);
  const int mtile = swz % 160;
  const int ntile = swz / 160;
  if (mtile >= nmt) return;
  const int4 wk = ((const int4*)(wsi + 2048))[mtile];
  const int e = wk.x, row_base = wk.y, rows = wk.z;
  const int n0 = ntile * 256;

  __shared__ short As[128 * 32];   // 8 KB
  __shared__ short Bs[256 * 32];   // 16 KB

  const int tid = threadIdx.x;
  const short* ws2 = ISB ? (const short*)w2g : w2b;
  const short* zp  = (const short*)(wsi + 3584);

  const int rr = tid >> 2;
  const int cc = (tid & 3) << 3;
  const bool va0 = rr < rows;
  const bool va1 = (64 + rr) < rows;
  const short* ag0 = va0 ? H + (size_t)(row_base + rr) * NI + cc : zp;
  const short* ag1 = va1 ? H + (size_t)(row_base + 64 + rr) * NI + cc : zp;
  const int sa0 = va0 ? 32 : 0;
  const int sa1 = va1 ? 32 : 0;
  const short* bg0 = ws2 + ((size_t)e * ND + n0 + rr)       * NI + cc;
  const short* bg1 = ws2 + ((size_t)e * ND + n0 + 64  + rr) * NI + cc;
  const short* bg2 = ws2 + ((size_t)e * ND + n0 + 128 + rr) * NI + cc;
  const short* bg3 = ws2 + ((size_t)e * ND + n0 + 192 + rr) * NI + cc;

  short* la0 = &As[(size_t)tid * 8];
  short* la1 = &As[((size_t)tid + 256) * 8];
  short* lb0 = &Bs[(size_t)tid * 8];
  short* lb1 = &Bs[((size_t)tid + 256) * 8];
  short* lb2 = &Bs[((size_t)tid + 512) * 8];
  short* lb3 = &Bs[((size_t)tid + 768) * 8];

  const int lane = tid & 63;
  const int wv = tid >> 6;
  const int wm = (wv >> 1) << 6;   // 0/64
  const int wn = (wv & 1) << 7;    // 0/128
  const int r16 = lane & 15;
  const int qd  = lane >> 4;
  const int qd8 = qd << 3;

  f32x4 acc[4][8] = {};

  for (int kt = 0; kt < NI; kt += 32){
    __syncthreads();
    gl16(ag0, la0); gl16(ag1, la1);
    gl16(bg0, lb0); gl16(bg1, lb1);
    gl16(bg2, lb2); gl16(bg3, lb3);
    ag0 += sa0; ag1 += sa1;
    bg0 += 32; bg1 += 32; bg2 += 32; bg3 += 32;
    __syncthreads();
    bf16x8 af[4], bf[8];
    #pragma unroll
    for (int mi = 0; mi < 4; mi++)
      af[mi] = *(const bf16x8*)&As[(wm + mi*16 + r16) * 32 + qd8];
    #pragma unroll
    for (int ni = 0; ni < 8; ni++)
      bf[ni] = *(const bf16x8*)&Bs[(wn + ni*16 + r16) * 32 + qd8];
    #pragma unroll
    for (int mi = 0; mi < 4; mi++)
      #pragma unroll
      for (int ni = 0; ni < 8; ni++)
        acc[mi][ni] = __builtin_amdgcn_mfma_f32_16x16x32_bf16(af[mi], bf[ni], acc[mi][ni], 0, 0, 0);
  }

  #pragma unroll
  for (int mi = 0; mi < 4; mi++){
    #pragma unroll
    for (int r = 0; r < 4; r++){
      int m = wm + mi*16 + qd*4 + r;
      if (m >= rows) continue;
      int p = list[row_base + m];
      float sc = ISB ? b2f(((const short*)rw)[p]) : ((const float*)rw)[p];
      size_t orow = (size_t)p * ND + n0 + wn;
      #pragma unroll
      for (int ni = 0; ni < 8; ni++){
        float v = acc[mi][ni][r] * sc;
        if (ISB) ((short*)out)[orow + ni*16 + r16] = f2b(v);
        else     ((float*)out)[orow + ni*16 + r16] = v;
      }
    }
  }
}

// ---------------- fallback (small workspace): previous verified 64x64 path ----------------

template<int ISB>
__device__ __forceinline__ void stage8(short* dst, const void* base, size_t off, bool valid){
  if (ISB){
    bf16x8 v = valid ? *(const bf16x8*)((const short*)base + off) : (bf16x8)0;
    *(bf16x8*)dst = v;
  } else {
    if (valid){
      const float4* s = (const float4*)((const float*)base + off);
      float4 a = s[0], b = s[1];
      dst[0]=f2b(a.x); dst[1]=f2b(a.y); dst[2]=f2b(a.z); dst[3]=f2b(a.w);
      dst[4]=f2b(b.x); dst[5]=f2b(b.y); dst[6]=f2b(b.z); dst[7]=f2b(b.w);
    } else {
      *(bf16x8*)dst = (bf16x8)0;
    }
  }
}

#define LDS_STRIDE 40

template<int ISB>
__global__ __launch_bounds__(256)
void pass1_kernel(const void* __restrict__ x, const void* __restrict__ w0,
                  const void* __restrict__ w1, const int* __restrict__ wsi,
                  const int* __restrict__ list, short* __restrict__ H)
{
  if (wsi[32] != ISB) return;
  if ((int)blockIdx.x >= wsi[33]) return;
  const int4 wk = ((const int4*)(wsi + 64))[blockIdx.x];
  const int e = wk.x, row_base = wk.y, rows = wk.z;
  const int n0 = blockIdx.y * 64;

  __shared__ short As [64 * LDS_STRIDE];
  __shared__ short B0s[64 * LDS_STRIDE];
  __shared__ short B1s[64 * LDS_STRIDE];

  const int tid = threadIdx.x;
  const int lr  = tid >> 2;
  const int c8  = (tid & 3) << 3;
  const bool avalid = lr < rows;
  size_t abase = 0;
  if (avalid){
    int tok = list[row_base + lr] >> 2;
    abase = (size_t)tok * ND + c8;
  }
  const size_t bbase = ((size_t)e * NI + (size_t)(n0 + lr)) * (size_t)ND + c8;

  const int lane = tid & 63;
  const int wv = tid >> 6;
  const int wm = (wv >> 1) << 5;
  const int wn = (wv & 1) << 5;
  const int r16 = lane & 15;
  const int qd  = lane >> 4;
  const int qd8 = qd << 3;

  f32x4 acc0[2][2] = {};
  f32x4 acc1[2][2] = {};

  short* a_dst  = &As [lr * LDS_STRIDE + c8];
  short* b0_dst = &B0s[lr * LDS_STRIDE + c8];
  short* b1_dst = &B1s[lr * LDS_STRIDE + c8];

  for (int kt = 0; kt < ND; kt += 32){
    __syncthreads();
    stage8<ISB>(a_dst,  x,  abase + kt, avalid);
    stage8<ISB>(b0_dst, w0, bbase + kt, true);
    stage8<ISB>(b1_dst, w1, bbase + kt, true);
    __syncthreads();
    bf16x8 af[2], b0f[2], b1f[2];
    #pragma unroll
    for (int mi = 0; mi < 2; mi++)
      af[mi] = *(const bf16x8*)&As[(wm + mi*16 + r16) * LDS_STRIDE + qd8];
    #pragma unroll
    for (int ni = 0; ni < 2; ni++){
      b0f[ni] = *(const bf16x8*)&B0s[(wn + ni*16 + r16) * LDS_STRIDE + qd8];
      b1f[ni] = *(const bf16x8*)&B1s[(wn + ni*16 + r16) * LDS_STRIDE + qd8];
    }
    #pragma unroll
    for (int mi = 0; mi < 2; mi++)
      #pragma unroll
      for (int ni = 0; ni < 2; ni++){
        acc0[mi][ni] = __builtin_amdgcn_mfma_f32_16x16x32_bf16(af[mi], b0f[ni], acc0[mi][ni], 0, 0, 0);
        acc1[mi][ni] = __builtin_amdgcn_mfma_f32_16x16x32_bf16(af[mi], b1f[ni], acc1[mi][ni], 0, 0, 0);
      }
  }

  #pragma unroll
  for (int mi = 0; mi < 2; mi++){
    #pragma unroll
    for (int r = 0; r < 4; r++){
      int m = wm + mi*16 + qd*4 + r;
      if (m >= rows) continue;
      size_t hrow = (size_t)(row_base + m) * NI + n0;
      #pragma unroll
      for (int ni = 0; ni < 2; ni++){
        float a0v = acc0[mi][ni][r];
        float a1v = acc1[mi][ni][r];
        float hv = (a0v / (1.f + __expf(-a0v))) * a1v;
        H[hrow + wn + ni*16 + r16] = f2b(hv);
      }
    }
  }
}

template<int ISB>
__global__ __launch_bounds__(256)
void pass2_kernel(const void* __restrict__ w2, const void* __restrict__ rw,
                  const int* __restrict__ wsi, const int* __restrict__ list,
                  const short* __restrict__ H, void* __restrict__ out)
{
  if (wsi[32] != ISB) return;
  if ((int)blockIdx.x >= wsi[33]) return;
  const int4 wk = ((const int4*)(wsi + 64))[blockIdx.x];
  const int e = wk.x, row_base = wk.y, rows = wk.z;
  const int n0 = blockIdx.y * 64;

  __shared__ short As[64 * LDS_STRIDE];
  __shared__ short Bs[64 * LDS_STRIDE];

  const int tid = threadIdx.x;
  const int lr  = tid >> 2;
  const int c8  = (tid & 3) << 3;
  const bool avalid = lr < rows;
  const size_t abase = (size_t)(row_base + lr) * NI + c8;
  const size_t bbase = ((size_t)e * ND + (size_t)(n0 + lr)) * (size_t)NI + c8;

  const int lane = tid & 63;
  const int wv = tid >> 6;
  const int wm = (wv >> 1) << 5;
  const int wn = (wv & 1) << 5;
  const int r16 = lane & 15;
  const int qd  = lane >> 4;
  const int qd8 = qd << 3;

  f32x4 acc[2][2] = {};

  short* a_dst = &As[lr * LDS_STRIDE + c8];
  short* b_dst = &Bs[lr * LDS_STRIDE + c8];

  for (int kt = 0; kt < NI; kt += 32){
    __syncthreads();
    {
      bf16x8 v = avalid ? *(const bf16x8*)&H[abase + kt] : (bf16x8)0;
      *(bf16x8*)a_dst = v;
    }
    stage8<ISB>(b_dst, w2, bbase + kt, true);
    __syncthreads();
    bf16x8 af[2], bf[2];
    #pragma unroll
    for (int mi = 0; mi < 2; mi++)
      af[mi] = *(const bf16x8*)&As[(wm + mi*16 + r16) * LDS_STRIDE + qd8];
    #pragma unroll
    for (int ni = 0; ni < 2; ni++)
      bf[ni] = *(const bf16x8*)&Bs[(wn + ni*16 + r16) * LDS_STRIDE + qd8];
    #pragma unroll
    for (int mi = 0; mi < 2; mi++)
      #pragma unroll
      for (int ni = 0; ni < 2; ni++)
        acc[mi][ni] = __builtin_amdgcn_mfma_f32_16x16x32_bf16(af[mi], bf[ni], acc[mi][ni], 0, 0, 0);
  }

  #pragma unroll
  for (int mi = 0; mi < 2; mi++){
    #pragma unroll
    for (int r = 0; r < 4; r++){
      int m = wm + mi*16 + qd*4 + r;
      if (m >= rows) continue;
      int p = list[row_base + m];
      float sc = ISB ? b2f(((const short*)rw)[p]) : ((const float*)rw)[p];
      size_t orow = (size_t)p * ND + n0;
      #pragma unroll
      for (int ni = 0; ni < 2; ni++){
        float v = acc[mi][ni][r] * sc;
        if (ISB) ((short*)out)[orow + wn + ni*16 + r16] = f2b(v);
        else     ((float*)out)[orow + wn + ni*16 + r16] = v;
      }
    }
  }
}

// ---------------- launch ----------------

extern "C" void kernel_launch(void* const* d_in, const int* in_sizes, int n_in,
                              void* d_out, int out_size, void* d_ws, size_t ws_size,
                              hipStream_t stream) {
  (void)in_sizes; (void)n_in; (void)out_size;
  const void* x  = d_in[0];
  const void* w0 = d_in[1];
  const void* w1 = d_in[2];
  const void* w2 = d_in[3];
  const int* sel = (const int*)d_in[4];
  const void* rw = d_in[5];

  int* wsi   = (int*)d_ws;
  int* list  = wsi + 4096;
  short* H   = (short*)((char*)d_ws + 262144);

  const size_t H_BYTES  = (size_t)NTK * NI * 2;          // 46,137,344
  const size_t XB_BYTES = (size_t)NT * ND * 2;           // 16,777,216
  const size_t WB_BYTES = (size_t)NE * NI * ND * 2;      // 92,274,688
  const size_t offX = 262144 + H_BYTES;
  const size_t offW = offX + XB_BYTES;
  const size_t need = offW + 2 * WB_BYTES;               // ~247.7 MB

  detect_init_kernel<<<1, 256, 0, stream>>>((const unsigned short*)x, wsi);
  hist_kernel<<<NTK/256, 256, 0, stream>>>(sel, wsi);
  plan_kernel<<<1, 64, 0, stream>>>(wsi);
  scatter_kernel<<<NTK/256, 256, 0, stream>>>(sel, wsi, list);

  if (ws_size >= need){
    short* xb  = (short*)((char*)d_ws + offX);
    short* w0b = (short*)((char*)d_ws + offW);
    short* w1b = w0b + (size_t)NE * NI * ND;
    short* w2b = w0b;   // overlays w0b AFTER pass1 consumed it (stream-ordered)

    conv_kernel<<<2048, 256, 0, stream>>>((const float*)x,  xb,  NT*ND/8,    wsi);
    conv_kernel<<<2048, 256, 0, stream>>>((const float*)w0, w0b, NE*NI*ND/8, wsi);
    conv_kernel<<<2048, 256, 0, stream>>>((const float*)w1, w1b, NE*NI*ND/8, wsi);

    dim3 g1(160, NI/128);   // 160 x 11 = 1760 blocks (divisible by 8)
    pass1b_kernel<1><<<g1, 256, 0, stream>>>(x, w0, w1, xb, w0b, w1b, wsi, list, H);
    pass1b_kernel<0><<<g1, 256, 0, stream>>>(x, w0, w1, xb, w0b, w1b, wsi, list, H);

    conv_kernel<<<2048, 256, 0, stream>>>((const float*)w2, w2b, NE*ND*NI/8, wsi);

    dim3 g2(160, ND/256);   // 160 x 8 = 1280 blocks (divisible by 8)
    pass2b_kernel<1><<<g2, 256, 0, stream>>>(w2, rw, w2b, wsi, list, H, d_out);
    pass2b_kernel<0><<<g2, 256, 0, stream>>>(w2, rw, w2b, wsi, list, H, d_out);
  } else {
    dim3 g1(272, NI/64);
    dim3 g2(272, ND/64);
    pass1_kernel<1><<<g1, 256, 0, stream>>>(x, w0, w1, wsi, list, H);
    pass1_kernel<0><<<g1, 256, 0, stream>>>(x, w0, w1, wsi, list, H);
    pass2_kernel<1><<<g2, 256, 0, stream>>>(w2, rw, wsi, list, H, d_out);
    pass2_kernel<0><<<g2, 256, 0, stream>>>(w2, rw, wsi, list, H, d_out);
  }
}

// Round 3
// 1103.071 us; speedup vs baseline: 1.6045x; 1.0246x over previous
//
#include <hip/hip_runtime.h>
#include <hip/hip_bf16.h>
#include <stdint.h>

// Problem constants
#define NT 4096      // tokens
#define ND 2048      // hidden dim
#define NE 16        // experts
#define NI 1408      // intermediate dim
#define NK 4         // top-k
#define NTK (NT*NK)  // 16384 pair-rows

typedef __attribute__((ext_vector_type(8))) short bf16x8;   // 8 bf16 = 4 VGPRs (MFMA a/b frag)
typedef __attribute__((ext_vector_type(4))) float f32x4;    // MFMA 16x16 acc frag

__device__ __forceinline__ short f2b(float f){
  uint32_t u = __float_as_uint(f);
  uint32_t r = (u + 0x7fffu + ((u >> 16) & 1u)) >> 16;   // RNE
  return (short)(uint16_t)r;
}
__device__ __forceinline__ float b2f(short s){
  return __uint_as_float(((uint32_t)(uint16_t)s) << 16);
}

// async 16B global -> LDS (wave-uniform LDS base + lane*16; per-lane global addr)
__device__ __forceinline__ void gl16(const void* g, void* l){
  __builtin_amdgcn_global_load_lds(
      (const __attribute__((address_space(1))) void*)g,
      (__attribute__((address_space(3))) void*)l, 16, 0, 0);
}

// XCD-chunked bijective swizzle (nwg divisible by 8): each XCD owns a contiguous
// swz range; consecutive swz on one XCD walk consecutive M-tiles sharing a B-panel.
__device__ __forceinline__ int xcd_swz(int lin, int nwg){
  int cpx = nwg >> 3;
  return (lin & 7) * cpx + (lin >> 3);
}

// Workspace int layout (wsi = (int*)d_ws):
// [0..16)      counts per expert
// [16..32)     scatter cursors
// [32]         flag_bf16 (1 = inputs bf16, 0 = fp32)
// [33]         n_work64   [34] n_work128
// [40..57)     offsets (exclusive prefix of counts)
// [64..1152)   work64 list: int4 {e, row_base, rows, 0} x 272
// [2048..2688) work128 list: int4 {e, row_base, rows, 0} x 160
// [3584..3840) zero page (1 KB, 16B aligned) for invalid-row global_load_lds
// [4096..4096+NTK) list: pair id p = t*NK+k, grouped by expert
// byte 262144:             H   bf16 NTK x NI   (46.14 MB)
// byte 262144+H:           xb  bf16 NT x ND    (16.78 MB)
// byte ...+xb:             w0b bf16 E x NI x ND (92.27 MB)
// byte ...+w0b:            w1b bf16 E x NI x ND (92.27 MB)
// big3 path (ws >= ~340MB): w2b bf16 E x ND x I after w1b (no overlay)
// mid  path:                w2b overlays w0b after pass1 (stream-ordered)

// ---------------- routing ----------------

__global__ void detect_init_kernel(const unsigned short* xu, int* wsi){
  const int tid = threadIdx.x;
  if (tid < 64) wsi[tid] = 0;     // counts, cursors, flag, n_work
  wsi[3584 + tid] = 0;            // zero page
  __shared__ int red[256];
  // If x is genuine bf16 N(0,1), no element has |v| >= 32 (exp field >= 132).
  // If x is fp32, the low halves of each float are ~uniform bits -> ~48% trip it.
  int c = 0;
  for (int i = tid; i < 8192; i += 256){
    int ex = (xu[i] >> 7) & 0xff;
    c += (ex >= 132) ? 1 : 0;
  }
  red[tid] = c;
  __syncthreads();
  if (tid == 0){
    int s = 0;
    for (int i = 0; i < 256; i++) s += red[i];
    wsi[32] = (s < 64) ? 1 : 0;
  }
}

__global__ void hist_kernel(const int* __restrict__ sel, int* wsi){
  int i = blockIdx.x * 256 + threadIdx.x;
  if (i < NTK) atomicAdd(&wsi[sel[i]], 1);
}

// one wave: prefix sums via shfl, parallel per-expert tile emission
__global__ void plan_kernel(int* wsi){
  const int lane = threadIdx.x;           // 0..63
  int c = (lane < NE) ? wsi[lane] : 0;
  int off = 0, tb128 = 0, tb64 = 0;
  int nm128 = (c + 127) >> 7;
  int nm64  = (c + 63) >> 6;
  for (int e = 0; e < NE; e++){
    int ce  = __shfl(c, e, 64);
    int t1  = __shfl(nm128, e, 64);
    int t0  = __shfl(nm64, e, 64);
    if (e < lane){ off += ce; tb128 += t1; tb64 += t0; }
  }
  if (lane < NE){
    wsi[40 + lane] = off;
    int4* work128 = (int4*)(wsi + 2048);
    for (int mt = 0; mt < nm128; mt++){
      int rem = c - mt * 128;
      work128[tb128 + mt] = make_int4(lane, off + mt * 128, rem < 128 ? rem : 128, 0);
    }
    int4* work64 = (int4*)(wsi + 64);
    for (int mt = 0; mt < nm64; mt++){
      int rem = c - mt * 64;
      work64[tb64 + mt] = make_int4(lane, off + mt * 64, rem < 64 ? rem : 64, 0);
    }
  }
  int tot128 = __shfl(tb128 + nm128, NE - 1, 64);
  int tot64  = __shfl(tb64 + nm64, NE - 1, 64);
  if (lane == 0){ wsi[33] = tot64; wsi[34] = tot128; }
}

__global__ void scatter_kernel(const int* __restrict__ sel, int* wsi, int* list){
  int i = blockIdx.x * 256 + threadIdx.x;
  if (i < NTK){
    int e = sel[i];
    int pos = atomicAdd(&wsi[16 + e], 1);
    list[wsi[40 + e] + pos] = i;
  }
}

// ---------------- fp32 -> bf16 conversion ----------------
// 16B/lane unit-stride reads, 8B stores.

__global__ __launch_bounds__(256)
void conv1_kernel(const float* __restrict__ src, short* __restrict__ dst,
                  long n4, const int* __restrict__ wsi){
  if (wsi[32]) return;
  const long stride = (long)gridDim.x * 256;
  for (long i = (long)blockIdx.x * 256 + threadIdx.x; i < n4; i += stride){
    float4 a = ((const float4*)src)[i];
    short4 v; v.x = f2b(a.x); v.y = f2b(a.y); v.z = f2b(a.z); v.w = f2b(a.w);
    *(short4*)(dst + i * 4) = v;
  }
}

// all four tensors in one launch (big3 path)
__global__ __launch_bounds__(256)
void conv4_kernel(const float* __restrict__ x, const float* __restrict__ w0,
                  const float* __restrict__ w1, const float* __restrict__ w2,
                  short* __restrict__ xb, short* __restrict__ w0b,
                  short* __restrict__ w1b, short* __restrict__ w2b,
                  const int* __restrict__ wsi){
  if (wsi[32]) return;
  const long NX = (long)NT * ND / 4;
  const long NW = (long)NE * NI * ND / 4;
  const long total = NX + 3 * NW;
  const long stride = (long)gridDim.x * 256;
  for (long i = (long)blockIdx.x * 256 + threadIdx.x; i < total; i += stride){
    const float4* s; short* d; long j;
    if (i < NX)            { s = (const float4*)x;  d = xb;  j = i; }
    else if (i < NX + NW)  { s = (const float4*)w0; d = w0b; j = i - NX; }
    else if (i < NX + 2*NW){ s = (const float4*)w1; d = w1b; j = i - NX - NW; }
    else                   { s = (const float4*)w2; d = w2b; j = i - NX - 2*NW; }
    float4 a = s[j];
    short4 v; v.x = f2b(a.x); v.y = f2b(a.y); v.z = f2b(a.z); v.w = f2b(a.w);
    *(short4*)(d + j * 4) = v;
  }
}

// ---------------- big-ws pass 1: BM=128, BN=128 (w0 & w1 each), BK=32 ----------------
// Double-buffered LDS; per step: ds_read frags(buf) -> issue next stage(buf^1) -> MFMA -> barrier.
// grid: (160, NI/128=11) = 1760 blocks (divisible by 8).

template<int ISB>
__global__ __launch_bounds__(256, 2)
void pass1b_kernel(const void* __restrict__ xg, const void* __restrict__ w0g,
                   const void* __restrict__ w1g,
                   const short* __restrict__ xb, const short* __restrict__ w0b,
                   const short* __restrict__ w1b,
                   const int* __restrict__ wsi, const int* __restrict__ list,
                   short* __restrict__ H)
{
  if (wsi[32] != ISB) return;
  const int nmt = wsi[34];
  const int lin = blockIdx.x + 160 * blockIdx.y;
  const int swz = xcd_swz(lin, 160 * gridDim.y);
  const int mtile = swz % 160;
  const int ntile = swz / 160;
  if (mtile >= nmt) return;
  const int4 wk = ((const int4*)(wsi + 2048))[mtile];
  const int e = wk.x, row_base = wk.y, rows = wk.z;
  const int n0 = ntile * 128;

  __shared__ short As [2 * 128 * 32];   // 16 KB (double-buffered)
  __shared__ short B0s[2 * 128 * 32];   // 16 KB
  __shared__ short B1s[2 * 128 * 32];   // 16 KB

  const int tid = threadIdx.x;
  const short* xs  = ISB ? (const short*)xg  : xb;
  const short* w0s = ISB ? (const short*)w0g : w0b;
  const short* w1s = ISB ? (const short*)w1g : w1b;
  const short* zp  = (const short*)(wsi + 3584);

  const int rr = tid >> 2;              // 0..63
  const int cc = (tid & 3) << 3;        // k-offset 0/8/16/24
  const bool va0 = rr < rows;
  const bool va1 = (64 + rr) < rows;
  const int t0 = va0 ? (list[row_base + rr] >> 2) : 0;
  const int t1 = va1 ? (list[row_base + 64 + rr] >> 2) : 0;
  const short* ag0 = va0 ? xs + (size_t)t0 * ND + cc : zp;
  const short* ag1 = va1 ? xs + (size_t)t1 * ND + cc : zp;
  const int sa0 = va0 ? 32 : 0;
  const int sa1 = va1 ? 32 : 0;
  const short* b0g0 = w0s + ((size_t)e * NI + n0 + rr)      * ND + cc;
  const short* b0g1 = w0s + ((size_t)e * NI + n0 + 64 + rr) * ND + cc;
  const short* b1g0 = w1s + ((size_t)e * NI + n0 + rr)      * ND + cc;
  const short* b1g1 = w1s + ((size_t)e * NI + n0 + 64 + rr) * ND + cc;

  short* la0  = &As [(size_t)tid * 8];
  short* la1  = &As [((size_t)tid + 256) * 8];
  short* lb00 = &B0s[(size_t)tid * 8];
  short* lb01 = &B0s[((size_t)tid + 256) * 8];
  short* lb10 = &B1s[(size_t)tid * 8];
  short* lb11 = &B1s[((size_t)tid + 256) * 8];

  const int lane = tid & 63;
  const int wv = tid >> 6;
  const int wm = (wv >> 1) << 6;   // 0/64
  const int wn = (wv & 1) << 6;    // 0/64
  const int r16 = lane & 15;
  const int qd  = lane >> 4;
  const int qd8 = qd << 3;

  f32x4 acc0[4][4] = {};
  f32x4 acc1[4][4] = {};

  const int nst = ND / 32;   // 64
  // prologue: stage step 0 into buf0
  gl16(ag0,  la0);  gl16(ag1,  la1);
  gl16(b0g0, lb00); gl16(b0g1, lb01);
  gl16(b1g0, lb10); gl16(b1g1, lb11);
  ag0 += sa0; ag1 += sa1;
  b0g0 += 32; b0g1 += 32; b1g0 += 32; b1g1 += 32;
  __syncthreads();             // drains vmcnt -> buf0 valid

  for (int t = 0; t < nst; ++t){
    const int bo = (t & 1) << 12;         // current buffer (shorts)
    const int bn = ((t + 1) & 1) << 12;   // next buffer
    bf16x8 af[4], b0f[4], b1f[4];
    #pragma unroll
    for (int mi = 0; mi < 4; mi++)
      af[mi] = *(const bf16x8*)&As[bo + (wm + mi*16 + r16) * 32 + qd8];
    #pragma unroll
    for (int ni = 0; ni < 4; ni++){
      b0f[ni] = *(const bf16x8*)&B0s[bo + (wn + ni*16 + r16) * 32 + qd8];
      b1f[ni] = *(const bf16x8*)&B1s[bo + (wn + ni*16 + r16) * 32 + qd8];
    }
    if (t + 1 < nst){
      gl16(ag0,  la0  + bn); gl16(ag1,  la1  + bn);
      gl16(b0g0, lb00 + bn); gl16(b0g1, lb01 + bn);
      gl16(b1g0, lb10 + bn); gl16(b1g1, lb11 + bn);
      ag0 += sa0; ag1 += sa1;
      b0g0 += 32; b0g1 += 32; b1g0 += 32; b1g1 += 32;
    }
    #pragma unroll
    for (int mi = 0; mi < 4; mi++)
      #pragma unroll
      for (int ni = 0; ni < 4; ni++){
        acc0[mi][ni] = __builtin_amdgcn_mfma_f32_16x16x32_bf16(af[mi], b0f[ni], acc0[mi][ni], 0, 0, 0);
        acc1[mi][ni] = __builtin_amdgcn_mfma_f32_16x16x32_bf16(af[mi], b1f[ni], acc1[mi][ni], 0, 0, 0);
      }
    __syncthreads();           // drains next-tile loads; buf swap safe
  }

  // epilogue: C[m = qd*4+reg][n = lane&15]
  #pragma unroll
  for (int mi = 0; mi < 4; mi++){
    #pragma unroll
    for (int r = 0; r < 4; r++){
      int m = wm + mi*16 + qd*4 + r;
      if (m >= rows) continue;
      size_t hrow = (size_t)(row_base + m) * NI + n0 + wn;
      #pragma unroll
      for (int ni = 0; ni < 4; ni++){
        float a0v = acc0[mi][ni][r];
        float a1v = acc1[mi][ni][r];
        float hv = (a0v / (1.f + __expf(-a0v))) * a1v;   // silu(a0)*a1
        H[hrow + ni*16 + r16] = f2b(hv);
      }
    }
  }
}

// ---------------- big-ws pass 2: BM=128, BN=256, BK=32, double-buffered ----------------
// grid: (160, ND/256=8) = 1280 blocks (divisible by 8).

template<int ISB>
__global__ __launch_bounds__(256, 2)
void pass2b_kernel(const void* __restrict__ w2g, const void* __restrict__ rw,
                   const short* __restrict__ w2b,
                   const int* __restrict__ wsi, const int* __restrict__ list,
                   const short* __restrict__ H, void* __restrict__ out)
{
  if (wsi[32] != ISB) return;
  const int nmt = wsi[34];
  const int lin = blockIdx.x + 160 * blockIdx.y;
  const int swz = xcd_swz(lin, 160 * gridDim.y);
  const int mtile = swz % 160;
  const int ntile = swz / 160;
  if (mtile >= nmt) return;
  const int4 wk = ((const int4*)(wsi + 2048))[mtile];
  const int e = wk.x, row_base = wk.y, rows = wk.z;
  const int n0 = ntile * 256;

  __shared__ short As[2 * 128 * 32];   // 16 KB
  __shared__ short Bs[2 * 256 * 32];   // 32 KB

  const int tid = threadIdx.x;
  const short* ws2 = ISB ? (const short*)w2g : w2b;
  const short* zp  = (const short*)(wsi + 3584);

  const int rr = tid >> 2;
  const int cc = (tid & 3) << 3;
  const bool va0 = rr < rows;
  const bool va1 = (64 + rr) < rows;
  const short* ag0 = va0 ? H + (size_t)(row_base + rr) * NI + cc : zp;
  const short* ag1 = va1 ? H + (size_t)(row_base + 64 + rr) * NI + cc : zp;
  const int sa0 = va0 ? 32 : 0;
  const int sa1 = va1 ? 32 : 0;
  const short* bg0 = ws2 + ((size_t)e * ND + n0 + rr)       * NI + cc;
  const short* bg1 = ws2 + ((size_t)e * ND + n0 + 64  + rr) * NI + cc;
  const short* bg2 = ws2 + ((size_t)e * ND + n0 + 128 + rr) * NI + cc;
  const short* bg3 = ws2 + ((size_t)e * ND + n0 + 192 + rr) * NI + cc;

  short* la0 = &As[(size_t)tid * 8];
  short* la1 = &As[((size_t)tid + 256) * 8];
  short* lb0 = &Bs[(size_t)tid * 8];
  short* lb1 = &Bs[((size_t)tid + 256) * 8];
  short* lb2 = &Bs[((size_t)tid + 512) * 8];
  short* lb3 = &Bs[((size_t)tid + 768) * 8];

  const int lane = tid & 63;
  const int wv = tid >> 6;
  const int wm = (wv >> 1) << 6;   // 0/64
  const int wn = (wv & 1) << 7;    // 0/128
  const int r16 = lane & 15;
  const int qd  = lane >> 4;
  const int qd8 = qd << 3;

  f32x4 acc[4][8] = {};

  const int nst = NI / 32;   // 44
  gl16(ag0, la0); gl16(ag1, la1);
  gl16(bg0, lb0); gl16(bg1, lb1);
  gl16(bg2, lb2); gl16(bg3, lb3);
  ag0 += sa0; ag1 += sa1;
  bg0 += 32; bg1 += 32; bg2 += 32; bg3 += 32;
  __syncthreads();

  for (int t = 0; t < nst; ++t){
    const int abo = (t & 1) << 12;
    const int abn = ((t + 1) & 1) << 12;
    const int bbo = (t & 1) << 13;
    const int bbn = ((t + 1) & 1) << 13;
    bf16x8 af[4], bf[8];
    #pragma unroll
    for (int mi = 0; mi < 4; mi++)
      af[mi] = *(const bf16x8*)&As[abo + (wm + mi*16 + r16) * 32 + qd8];
    #pragma unroll
    for (int ni = 0; ni < 8; ni++)
      bf[ni] = *(const bf16x8*)&Bs[bbo + (wn + ni*16 + r16) * 32 + qd8];
    if (t + 1 < nst){
      gl16(ag0, la0 + abn); gl16(ag1, la1 + abn);
      gl16(bg0, lb0 + bbn); gl16(bg1, lb1 + bbn);
      gl16(bg2, lb2 + bbn); gl16(bg3, lb3 + bbn);
      ag0 += sa0; ag1 += sa1;
      bg0 += 32; bg1 += 32; bg2 += 32; bg3 += 32;
    }
    #pragma unroll
    for (int mi = 0; mi < 4; mi++)
      #pragma unroll
      for (int ni = 0; ni < 8; ni++)
        acc[mi][ni] = __builtin_amdgcn_mfma_f32_16x16x32_bf16(af[mi], bf[ni], acc[mi][ni], 0, 0, 0);
    __syncthreads();
  }

  #pragma unroll
  for (int mi = 0; mi < 4; mi++){
    #pragma unroll
    for (int r = 0; r < 4; r++){
      int m = wm + mi*16 + qd*4 + r;
      if (m >= rows) continue;
      int p = list[row_base + m];
      float sc = ISB ? b2f(((const short*)rw)[p]) : ((const float*)rw)[p];
      size_t orow = (size_t)p * ND + n0 + wn;
      #pragma unroll
      for (int ni = 0; ni < 8; ni++){
        float v = acc[mi][ni][r] * sc;
        if (ISB) ((short*)out)[orow + ni*16 + r16] = f2b(v);
        else     ((float*)out)[orow + ni*16 + r16] = v;
      }
    }
  }
}

// ---------------- fallback (small workspace): verified 64x64 path ----------------

template<int ISB>
__device__ __forceinline__ void stage8(short* dst, const void* base, size_t off, bool valid){
  if (ISB){
    bf16x8 v = valid ? *(const bf16x8*)((const short*)base + off) : (bf16x8)0;
    *(bf16x8*)dst = v;
  } else {
    if (valid){
      const float4* s = (const float4*)((const float*)base + off);
      float4 a = s[0], b = s[1];
      dst[0]=f2b(a.x); dst[1]=f2b(a.y); dst[2]=f2b(a.z); dst[3]=f2b(a.w);
      dst[4]=f2b(b.x); dst[5]=f2b(b.y); dst[6]=f2b(b.z); dst[7]=f2b(b.w);
    } else {
      *(bf16x8*)dst = (bf16x8)0;
    }
  }
}

#define LDS_STRIDE 40

template<int ISB>
__global__ __launch_bounds__(256)
void pass1_kernel(const void* __restrict__ x, const void* __restrict__ w0,
                  const void* __restrict__ w1, const int* __restrict__ wsi,
                  const int* __restrict__ list, short* __restrict__ H)
{
  if (wsi[32] != ISB) return;
  if ((int)blockIdx.x >= wsi[33]) return;
  const int4 wk = ((const int4*)(wsi + 64))[blockIdx.x];
  const int e = wk.x, row_base = wk.y, rows = wk.z;
  const int n0 = blockIdx.y * 64;

  __shared__ short As [64 * LDS_STRIDE];
  __shared__ short B0s[64 * LDS_STRIDE];
  __shared__ short B1s[64 * LDS_STRIDE];

  const int tid = threadIdx.x;
  const int lr  = tid >> 2;
  const int c8  = (tid & 3) << 3;
  const bool avalid = lr < rows;
  size_t abase = 0;
  if (avalid){
    int tok = list[row_base + lr] >> 2;
    abase = (size_t)tok * ND + c8;
  }
  const size_t bbase = ((size_t)e * NI + (size_t)(n0 + lr)) * (size_t)ND + c8;

  const int lane = tid & 63;
  const int wv = tid >> 6;
  const int wm = (wv >> 1) << 5;
  const int wn = (wv & 1) << 5;
  const int r16 = lane & 15;
  const int qd  = lane >> 4;
  const int qd8 = qd << 3;

  f32x4 acc0[2][2] = {};
  f32x4 acc1[2][2] = {};

  short* a_dst  = &As [lr * LDS_STRIDE + c8];
  short* b0_dst = &B0s[lr * LDS_STRIDE + c8];
  short* b1_dst = &B1s[lr * LDS_STRIDE + c8];

  for (int kt = 0; kt < ND; kt += 32){
    __syncthreads();
    stage8<ISB>(a_dst,  x,  abase + kt, avalid);
    stage8<ISB>(b0_dst, w0, bbase + kt, true);
    stage8<ISB>(b1_dst, w1, bbase + kt, true);
    __syncthreads();
    bf16x8 af[2], b0f[2], b1f[2];
    #pragma unroll
    for (int mi = 0; mi < 2; mi++)
      af[mi] = *(const bf16x8*)&As[(wm + mi*16 + r16) * LDS_STRIDE + qd8];
    #pragma unroll
    for (int ni = 0; ni < 2; ni++){
      b0f[ni] = *(const bf16x8*)&B0s[(wn + ni*16 + r16) * LDS_STRIDE + qd8];
      b1f[ni] = *(const bf16x8*)&B1s[(wn + ni*16 + r16) * LDS_STRIDE + qd8];
    }
    #pragma unroll
    for (int mi = 0; mi < 2; mi++)
      #pragma unroll
      for (int ni = 0; ni < 2; ni++){
        acc0[mi][ni] = __builtin_amdgcn_mfma_f32_16x16x32_bf16(af[mi], b0f[ni], acc0[mi][ni], 0, 0, 0);
        acc1[mi][ni] = __builtin_amdgcn_mfma_f32_16x16x32_bf16(af[mi], b1f[ni], acc1[mi][ni], 0, 0, 0);
      }
  }

  #pragma unroll
  for (int mi = 0; mi < 2; mi++){
    #pragma unroll
    for (int r = 0; r < 4; r++){
      int m = wm + mi*16 + qd*4 + r;
      if (m >= rows) continue;
      size_t hrow = (size_t)(row_base + m) * NI + n0;
      #pragma unroll
      for (int ni = 0; ni < 2; ni++){
        float a0v = acc0[mi][ni][r];
        float a1v = acc1[mi][ni][r];
        float hv = (a0v / (1.f + __expf(-a0v))) * a1v;
        H[hrow + wn + ni*16 + r16] = f2b(hv);
      }
    }
  }
}

template<int ISB>
__global__ __launch_bounds__(256)
void pass2_kernel(const void* __restrict__ w2, const void* __restrict__ rw,
                  const int* __restrict__ wsi, const int* __restrict__ list,
                  const short* __restrict__ H, void* __restrict__ out)
{
  if (wsi[32] != ISB) return;
  if ((int)blockIdx.x >= wsi[33]) return;
  const int4 wk = ((const int4*)(wsi + 64))[blockIdx.x];
  const int e = wk.x, row_base = wk.y, rows = wk.z;
  const int n0 = blockIdx.y * 64;

  __shared__ short As[64 * LDS_STRIDE];
  __shared__ short Bs[64 * LDS_STRIDE];

  const int tid = threadIdx.x;
  const int lr  = tid >> 2;
  const int c8  = (tid & 3) << 3;
  const bool avalid = lr < rows;
  const size_t abase = (size_t)(row_base + lr) * NI + c8;
  const size_t bbase = ((size_t)e * ND + (size_t)(n0 + lr)) * (size_t)NI + c8;

  const int lane = tid & 63;
  const int wv = tid >> 6;
  const int wm = (wv >> 1) << 5;
  const int wn = (wv & 1) << 5;
  const int r16 = lane & 15;
  const int qd  = lane >> 4;
  const int qd8 = qd << 3;

  f32x4 acc[2][2] = {};

  short* a_dst = &As[lr * LDS_STRIDE + c8];
  short* b_dst = &Bs[lr * LDS_STRIDE + c8];

  for (int kt = 0; kt < NI; kt += 32){
    __syncthreads();
    {
      bf16x8 v = avalid ? *(const bf16x8*)&H[abase + kt] : (bf16x8)0;
      *(bf16x8*)a_dst = v;
    }
    stage8<ISB>(b_dst, w2, bbase + kt, true);
    __syncthreads();
    bf16x8 af[2], bf[2];
    #pragma unroll
    for (int mi = 0; mi < 2; mi++)
      af[mi] = *(const bf16x8*)&As[(wm + mi*16 + r16) * LDS_STRIDE + qd8];
    #pragma unroll
    for (int ni = 0; ni < 2; ni++)
      bf[ni] = *(const bf16x8*)&Bs[(wn + ni*16 + r16) * LDS_STRIDE + qd8];
    #pragma unroll
    for (int mi = 0; mi < 2; mi++)
      #pragma unroll
      for (int ni = 0; ni < 2; ni++)
        acc[mi][ni] = __builtin_amdgcn_mfma_f32_16x16x32_bf16(af[mi], bf[ni], acc[mi][ni], 0, 0, 0);
  }

  #pragma unroll
  for (int mi = 0; mi < 2; mi++){
    #pragma unroll
    for (int r = 0; r < 4; r++){
      int m = wm + mi*16 + qd*4 + r;
      if (m >= rows) continue;
      int p = list[row_base + m];
      float sc = ISB ? b2f(((const short*)rw)[p]) : ((const float*)rw)[p];
      size_t orow = (size_t)p * ND + n0;
      #pragma unroll
      for (int ni = 0; ni < 2; ni++){
        float v = acc[mi][ni][r] * sc;
        if (ISB) ((short*)out)[orow + wn + ni*16 + r16] = f2b(v);
        else     ((float*)out)[orow + wn + ni*16 + r16] = v;
      }
    }
  }
}

// ---------------- launch ----------------

extern "C" void kernel_launch(void* const* d_in, const int* in_sizes, int n_in,
                              void* d_out, int out_size, void* d_ws, size_t ws_size,
                              hipStream_t stream) {
  (void)in_sizes; (void)n_in; (void)out_size;
  const void* x  = d_in[0];
  const void* w0 = d_in[1];
  const void* w1 = d_in[2];
  const void* w2 = d_in[3];
  const int* sel = (const int*)d_in[4];
  const void* rw = d_in[5];

  int* wsi   = (int*)d_ws;
  int* list  = wsi + 4096;
  short* H   = (short*)((char*)d_ws + 262144);

  const size_t H_BYTES  = (size_t)NTK * NI * 2;          // 46,137,344
  const size_t XB_BYTES = (size_t)NT * ND * 2;           // 16,777,216
  const size_t WB_BYTES = (size_t)NE * NI * ND * 2;      // 92,274,688
  const size_t offX  = 262144 + H_BYTES;
  const size_t offW  = offX + XB_BYTES;
  const size_t need2 = offW + 2 * WB_BYTES;              // ~247.7 MB (overlay path)
  const size_t need3 = offW + 3 * WB_BYTES;              // ~340.0 MB (no-overlay path)

  detect_init_kernel<<<1, 256, 0, stream>>>((const unsigned short*)x, wsi);
  hist_kernel<<<NTK/256, 256, 0, stream>>>(sel, wsi);
  plan_kernel<<<1, 64, 0, stream>>>(wsi);
  scatter_kernel<<<NTK/256, 256, 0, stream>>>(sel, wsi, list);

  if (ws_size >= need2){
    short* xb  = (short*)((char*)d_ws + offX);
    short* w0b = (short*)((char*)d_ws + offW);
    short* w1b = w0b + (size_t)NE * NI * ND;
    dim3 g1(160, NI/128);   // 1760 blocks
    dim3 g2(160, ND/256);   // 1280 blocks

    if (ws_size >= need3){
      short* w2b = w1b + (size_t)NE * NI * ND;
      conv4_kernel<<<4096, 256, 0, stream>>>((const float*)x, (const float*)w0,
                                             (const float*)w1, (const float*)w2,
                                             xb, w0b, w1b, w2b, wsi);
      pass1b_kernel<1><<<g1, 256, 0, stream>>>(x, w0, w1, xb, w0b, w1b, wsi, list, H);
      pass1b_kernel<0><<<g1, 256, 0, stream>>>(x, w0, w1, xb, w0b, w1b, wsi, list, H);
      pass2b_kernel<1><<<g2, 256, 0, stream>>>(w2, rw, w2b, wsi, list, H, d_out);
      pass2b_kernel<0><<<g2, 256, 0, stream>>>(w2, rw, w2b, wsi, list, H, d_out);
    } else {
      short* w2b = w0b;   // overlays w0b AFTER pass1 consumed it (stream-ordered)
      conv1_kernel<<<2048, 256, 0, stream>>>((const float*)x,  xb,  (long)NT*ND/4,    wsi);
      conv1_kernel<<<2048, 256, 0, stream>>>((const float*)w0, w0b, (long)NE*NI*ND/4, wsi);
      conv1_kernel<<<2048, 256, 0, stream>>>((const float*)w1, w1b, (long)NE*NI*ND/4, wsi);
      pass1b_kernel<1><<<g1, 256, 0, stream>>>(x, w0, w1, xb, w0b, w1b, wsi, list, H);
      pass1b_kernel<0><<<g1, 256, 0, stream>>>(x, w0, w1, xb, w0b, w1b, wsi, list, H);
      conv1_kernel<<<2048, 256, 0, stream>>>((const float*)w2, w2b, (long)NE*ND*NI/4, wsi);
      pass2b_kernel<1><<<g2, 256, 0, stream>>>(w2, rw, w2b, wsi, list, H, d_out);
      pass2b_kernel<0><<<g2, 256, 0, stream>>>(w2, rw, w2b, wsi, list, H, d_out);
    }
  } else {
    dim3 g1(272, NI/64);
    dim3 g2(272, ND/64);
    pass1_kernel<1><<<g1, 256, 0, stream>>>(x, w0, w1, wsi, list, H);
    pass1_kernel<0><<<g1, 256, 0, stream>>>(x, w0, w1, wsi, list, H);
    pass2_kernel<1><<<g2, 256, 0, stream>>>(w2, rw, wsi, list, H, d_out);
    pass2_kernel<0><<<g2, 256, 0, stream>>>(w2, rw, wsi, list, H, d_out);
  }
}